// Round 7
// baseline (319.990 us; speedup 1.0000x reference)
//
#include <hip/hip_runtime.h>
#include <cstdint>
#include <cstddef>

#define HID 128
#define SEQL 28
#define INP 28
#define NL 10
#define NC 10
#define BATCH 4096
#define BB 8              // batch rows per block -> grid 512 = 2 blocks/CU
#define STRD 136          // padded row stride in halfs (272 B, b128-aligned)
#define BUFH (16 * STRD)  // halfs per 16x128 activation buffer (rows 8-15 junk-but-contained)

typedef _Float16 half8 __attribute__((ext_vector_type(8)));
typedef _Float16 half4 __attribute__((ext_vector_type(4)));
typedef float    f32x4 __attribute__((ext_vector_type(4)));

// ---------------- ws layout (bytes) ----------------
// Wcat : [NL][HID][256] f16 : 655360 @ 0   row n: [Wih(128, l0 zero-padded) | Whh(128)]
// bias : [NL][HID] f32      : 5120   @ 655360   (b_ih + b_hh)
// seq  : [BATCH][SEQL][HID] f16 : 29360128 @ 660480 (group-boundary acts; reused h3 then h7)
#define WS_WCAT_OFF 0
#define WS_BIAS_OFF 655360
#define WS_SEQ_OFF  660480

__global__ void convert_weights(const float* __restrict__ Wih0,
                                const float* __restrict__ Wih,
                                const float* __restrict__ Whh,
                                const float* __restrict__ bih,
                                const float* __restrict__ bhh,
                                _Float16* __restrict__ Wcat,
                                float* __restrict__ bias) {
  int tg = blockIdx.x * blockDim.x + threadIdx.x;
  if (tg >= NL * HID * 16) return;
  int r = tg >> 4, seg = tg & 15;
  int l = r / HID, n = r % HID;
  int k0 = seg * 16;
  _Float16* dst = Wcat + (size_t)r * 256 + k0;
  if (l == 0) {
#pragma unroll
    for (int i = 0; i < 16; ++i) {
      int k = k0 + i;
      float v = 0.f;
      if (k < INP) v = Wih0[n * INP + k];
      else if (k >= HID) v = Whh[(size_t)n * HID + (k - HID)];
      dst[i] = (_Float16)v;
    }
  } else {
    const float* src = (k0 < HID)
        ? (Wih + ((size_t)(l - 1) * HID + n) * HID + k0)
        : (Whh + ((size_t)l * HID + n) * HID + (k0 - HID));
#pragma unroll
    for (int i = 0; i < 16; ++i) dst[i] = (_Float16)src[i];
  }
  if (seg == 0) bias[r] = bih[r] + bhh[r];
}

// tanh(v) = 1 - 2/(e^{2v}+1) from raw HW ops (5 VALU, 2 trans) — r6 win.
__device__ __forceinline__ float tanh_fast(float v) {
  float e = __builtin_amdgcn_exp2f(v * 2.8853900817779268f);  // e^(2v)
  float r = __builtin_amdgcn_rcpf(e + 1.f);
  return __builtin_fmaf(-2.f, r, 1.f);
}

// Light workgroup barrier: orders LDS (lgkmcnt(0)) but does NOT drain vmcnt.
__device__ __forceinline__ void barrier_light() {
  __builtin_amdgcn_sched_barrier(0);
  asm volatile("s_waitcnt lgkmcnt(0)" ::: "memory");
  __builtin_amdgcn_s_barrier();
  __builtin_amdgcn_sched_barrier(0);
}

// Round-7 = round-6 structure (147 us) with BB=16 -> 8: grid 512 = 2 blocks/CU.
// r6 counters showed VGPR_Count=124 <= 128 and LDS 42.5KB, i.e. the HW can
// host 4 waves/SIMD (16 waves/CU = 2 blocks) — occupancy was capped only by
// grid = 1 block/CU. r5 tried this but __launch_bounds__(512,4) forced the
// allocator to 64 regs -> 2GB spill; keeping (512,2) leaves regs at ~124 and
// the 2nd block co-schedules naturally. The second block's waves (independent
// barrier) fill the >50% issue-idle (VALU 28.5 + MFMA 20) of the convoy gaps.
// MFMA m-dim half junk (8 valid rows of 16): B-frag column r affects only D
// column r, so junk rows 8-15 never contaminate rows 0-7; global reads clamp
// (&7), global writes guard (lane15<8 / b<BB).
// LDS slots (BUFH halfs): X(p)=slot p; O(s,p)=slot 2+2s+p.
// Tick tau, pt=tau&1: slot s computes t=tau-s; INb = s? O(s-1,1-pt) : X(pt);
// Hb = O(s,1-pt); writes O(s,pt). ONE light barrier per tick. Depth-2 global
// prefetch. seq stores drain at group-boundary __syncthreads (vmcnt(0)).
__global__ __launch_bounds__(512, 2) void rnn_fused(
    const float* __restrict__ x,
    const _Float16* __restrict__ Wcat,
    const float* __restrict__ bias,
    const float* __restrict__ fcW,
    const float* __restrict__ fcb,
    _Float16* __restrict__ seq,
    float* __restrict__ out) {
  __shared__ _Float16 lds[BUFH * 10] __attribute__((aligned(16)));

  const int tid    = threadIdx.x;
  const int lane15 = tid & 15;        // batch row m (MFMA D col); >=8 junk
  const int quad   = (tid >> 4) & 3;  // MFMA quad -> n offset quad*4+r
  const int wid    = tid >> 6;
  const int s      = wid >> 1;        // layer slot 0..3
  const int nhalf  = wid & 1;         // n-half 0/1
  const int n0     = nhalf * 64;
  const int b0     = blockIdx.x * BB;
  // g>=1 fill: 16 rows x 32 segs of 4 halfs (512 threads); rows 8-15 dup row&7
  const int frow1  = tid >> 5;
  const int fseg1  = tid & 31;
  // g0 fill: 16 rows x 8 segs of 4 floats (128 threads)
  const int frow0  = tid >> 3;
  const int fc0    = (tid & 7) * 4;

  const int rdoff = lane15 * STRD + quad * 8;       // act-frag read base
  const int wroff = lane15 * STRD + n0 + quad * 4;  // D write base (+nn*16)

  half8 wf[4][8];     // weights [n-subtile][k-frag]: A-operand frags
  f32x4 bias4[4];     // bias[n0+nn*16+quad*4 .. +3]

  for (int g = 0; g < 3; ++g) {
    const int L = g * 4 + s;  // this wave's layer (>=NL -> idle slot)
    if (L < NL) {
      const _Float16* Wl = Wcat + (size_t)L * HID * 256;
#pragma unroll
      for (int nn = 0; nn < 4; ++nn) {
#pragma unroll
        for (int ks = 0; ks < 8; ++ks)
          wf[nn][ks] = *(const half8*)(Wl + (size_t)(n0 + nn * 16 + lane15) * 256 + ks * 32 + quad * 8);
        bias4[nn] = *(const f32x4*)(bias + L * HID + n0 + nn * 16 + quad * 4);
      }
    }
    // FULL barrier: prev group's LDS reads done before re-zeroing; per-wave
    // vmcnt(0) drain orders prev group's seq stores before this group's loads.
    __syncthreads();
    {
      uint4 z; z.x = z.y = z.z = z.w = 0u;
      for (int i = tid; i < (BUFH * 8) / 8; i += 512)
        ((uint4*)(lds + 2 * BUFH))[i] = z;
    }

    f32x4 pfx[2];     // g0 prefetch (f32 x, vectorized; seg 7 = zero), slot = t&1
    uint2 pfu[2];     // g1/g2 prefetch (f16 seq), slot = t&1

    auto load_next = [&](int t, int sl) {
      if (g == 0) {
        if (tid < 128) {
          const float* xb = x + ((size_t)(b0 + (frow0 & 7)) * SEQL + t) * INP;
          if (fc0 < INP) pfx[sl] = *(const f32x4*)(xb + fc0);  // 16B-aligned
          else { f32x4 z4 = {0.f, 0.f, 0.f, 0.f}; pfx[sl] = z4; }
        }
      } else {
        pfu[sl] = *(const uint2*)(seq + ((size_t)(b0 + (frow1 & 7)) * SEQL + t) * HID + fseg1 * 4);
      }
    };
    auto store_X = [&](int sl) {  // pf slot sl -> LDS X slot sl
      if (g == 0) {
        if (tid < 128) {
          _Float16 h4[4];
#pragma unroll
          for (int i = 0; i < 4; ++i) h4[i] = (_Float16)pfx[sl][i];
          *(uint2*)(lds + sl * BUFH + frow0 * STRD + fc0) = *(const uint2*)h4;
        }
      } else {
        *(uint2*)(lds + sl * BUFH + frow1 * STRD + fseg1 * 4) = pfu[sl];
      }
    };

    // prologue: t=0 into X[0] (visible after tick-0 barrier); t=1 in flight
    load_next(0, 0);
    store_X(0);
    load_next(1, 1);

    auto tick = [&](int tau, int pt) {
      barrier_light();
      if (tau + 2 < SEQL) load_next(tau + 2, pt);  // depth-2 prefetch
      const int t = tau - s;
      if (L < NL && (unsigned)t < SEQL) {
        const _Float16* INb = (s == 0) ? lds + pt * BUFH
                                       : lds + (2 + 2 * (s - 1) + (1 - pt)) * BUFH;
        const _Float16* Hb  = lds + (2 + 2 * s + (1 - pt)) * BUFH;
        _Float16*       Ob  = lds + (2 + 2 * s + pt) * BUFH;
        // seq store: only valid batch rows
        const bool wseq = (g < 2) && (s == 3) && (lane15 < BB);

        auto tw = [&](int nn, f32x4 av) {
          half4 o;
#pragma unroll
          for (int r = 0; r < 4; ++r) o[r] = (_Float16)tanh_fast(av[r]);
          *(half4*)(Ob + wroff + nn * 16) = o;
          if (wseq)
            *(half4*)(seq + ((size_t)(b0 + lane15) * SEQL + t) * HID + n0 + nn * 16 + quad * 4) = o;
        };

        if (g == 0 && s == 0) {
          // layer 0: x-input is only 32 k-wide (28 + pad)
          half8 ax = *(const half8*)(INb + rdoff);
          half8 ah[4];
#pragma unroll
          for (int ks = 0; ks < 4; ++ks) ah[ks] = *(const half8*)(Hb + rdoff + ks * 32);
          f32x4 a0 = bias4[0], a1 = bias4[1];
          a0 = __builtin_amdgcn_mfma_f32_16x16x32_f16(wf[0][0], ax, a0, 0, 0, 0);
          a1 = __builtin_amdgcn_mfma_f32_16x16x32_f16(wf[1][0], ax, a1, 0, 0, 0);
#pragma unroll
          for (int ks = 0; ks < 4; ++ks) {
            a0 = __builtin_amdgcn_mfma_f32_16x16x32_f16(wf[0][4 + ks], ah[ks], a0, 0, 0, 0);
            a1 = __builtin_amdgcn_mfma_f32_16x16x32_f16(wf[1][4 + ks], ah[ks], a1, 0, 0, 0);
          }
          f32x4 a2 = bias4[2], a3 = bias4[3];
          a2 = __builtin_amdgcn_mfma_f32_16x16x32_f16(wf[2][0], ax, a2, 0, 0, 0);
          a3 = __builtin_amdgcn_mfma_f32_16x16x32_f16(wf[3][0], ax, a3, 0, 0, 0);
#pragma unroll
          for (int ks = 0; ks < 4; ++ks) {
            a2 = __builtin_amdgcn_mfma_f32_16x16x32_f16(wf[2][4 + ks], ah[ks], a2, 0, 0, 0);
            a3 = __builtin_amdgcn_mfma_f32_16x16x32_f16(wf[3][4 + ks], ah[ks], a3, 0, 0, 0);
          }
          tw(0, a0); tw(1, a1); tw(2, a2); tw(3, a3);
        } else {
          // pre-read all 8 act frags once; two 2-wide accumulator pairs so
          // pair-0's tanh (TRANS/VALU) can overlap pair-1's MFMAs.
          half8 af[8];
#pragma unroll
          for (int ks = 0; ks < 4; ++ks) af[ks] = *(const half8*)(INb + rdoff + ks * 32);
#pragma unroll
          for (int ks = 0; ks < 4; ++ks) af[4 + ks] = *(const half8*)(Hb + rdoff + ks * 32);
          f32x4 a0 = bias4[0], a1 = bias4[1];
#pragma unroll
          for (int i = 0; i < 8; ++i) {
            a0 = __builtin_amdgcn_mfma_f32_16x16x32_f16(wf[0][i], af[i], a0, 0, 0, 0);
            a1 = __builtin_amdgcn_mfma_f32_16x16x32_f16(wf[1][i], af[i], a1, 0, 0, 0);
          }
          f32x4 a2 = bias4[2], a3 = bias4[3];
#pragma unroll
          for (int i = 0; i < 8; ++i) {
            a2 = __builtin_amdgcn_mfma_f32_16x16x32_f16(wf[2][i], af[i], a2, 0, 0, 0);
            a3 = __builtin_amdgcn_mfma_f32_16x16x32_f16(wf[3][i], af[i], a3, 0, 0, 0);
          }
          tw(0, a0); tw(1, a1); tw(2, a2); tw(3, a3);
        }
      }
      if (tau + 1 < SEQL) store_X(1 - pt);  // t=tau+1 -> X[(tau+1)&1]
    };

    const int Tend = (g == 2) ? 28 : 30;  // even; ticks 0..Tend
    for (int tau = 0; tau < Tend; tau += 2) {
      tick(tau, 0);
      tick(tau + 1, 1);
    }
    tick(Tend, 0);
  }
  __syncthreads();

  // --- FC on layer-9 h at t=27: slot s=1, written at g2 tick 28 (pt=0) -> slot 4 ---
  if (tid < 16 * NC) {
    int c = tid >> 4;
    int b = tid & 15;
    if (b < BB) {
      float acc = fcb[c];
      const float* wr = fcW + c * HID;
      const _Float16* hr = lds + BUFH * 4 + b * STRD;
#pragma unroll
      for (int k0 = 0; k0 < HID; k0 += 8) {
        half8 h = *(const half8*)(hr + k0);
        f32x4 w0 = *(const f32x4*)(wr + k0);
        f32x4 w1 = *(const f32x4*)(wr + k0 + 4);
#pragma unroll
        for (int j = 0; j < 4; ++j)
          acc += (float)h[j] * w0[j] + (float)h[j + 4] * w1[j];
      }
      out[(size_t)(b0 + b) * NC + c] = acc;
    }
  }
}

extern "C" void kernel_launch(void* const* d_in, const int* in_sizes, int n_in,
                              void* d_out, int out_size, void* d_ws, size_t ws_size,
                              hipStream_t stream) {
  const float* x    = (const float*)d_in[0];
  const float* Wih0 = (const float*)d_in[1];
  const float* Wih  = (const float*)d_in[2];
  const float* Whh  = (const float*)d_in[3];
  const float* bih  = (const float*)d_in[4];
  const float* bhh  = (const float*)d_in[5];
  const float* fcW  = (const float*)d_in[6];
  const float* fcb  = (const float*)d_in[7];
  float* out = (float*)d_out;

  _Float16* Wcat = (_Float16*)((char*)d_ws + WS_WCAT_OFF);
  float*    bs   = (float*)((char*)d_ws + WS_BIAS_OFF);
  _Float16* seq  = (_Float16*)((char*)d_ws + WS_SEQ_OFF);

  convert_weights<<<dim3(80), dim3(256), 0, stream>>>(Wih0, Wih, Whh, bih, bhh, Wcat, bs);
  rnn_fused<<<dim3(BATCH / BB), dim3(512), 0, stream>>>(x, Wcat, bs, fcW, fcb, seq, out);
}

// Round 8
// 180.506 us; speedup vs baseline: 1.7727x; 1.7727x over previous
//
#include <hip/hip_runtime.h>
#include <cstdint>
#include <cstddef>

#define HID 128
#define SEQL 28
#define INP 28
#define NL 10
#define NC 10
#define BATCH 4096
#define BB 16             // batch rows per block (1 block/CU — hard optimum, see r7 note)
#define STRD 136          // padded row stride in halfs (272 B, b128-aligned)
#define BUFH (16 * STRD)  // halfs per 16x128 activation buffer (4352 B)

// LDS slot map (dynamic shared, 37 slots x 4352 B = 161024 B <= 160 KiB):
//  0,1   : X(p)      g0 input staging (f32 x -> f16), parity p
//  2..7  : O(s,p) = 2+2s+p, s=0..2 (slot-3 has no O: it lives in SEQ)
//  8     : Z (all-zero; h_{-1} source for s3)
//  9..36 : SEQ(t) = 9+t, t=0..27 — the inter-group activation sequence
//          (g0: s3 writes h3[t]; g1: s0 reads h3[t], s3 overwrites with h7[t]
//           3 ticks later; g2: s0 reads h7[t]). Replaces the 57 MB global
//          seq round-trip of rounds 0-7 entirely.
#define NSLOT 37
#define LDS_BYTES (NSLOT * BUFH * 2)

typedef _Float16 half8 __attribute__((ext_vector_type(8)));
typedef _Float16 half4 __attribute__((ext_vector_type(4)));
typedef float    f32x4 __attribute__((ext_vector_type(4)));

// ---------------- ws layout (bytes) ----------------
// Wcat : [NL][HID][256] f16 : 655360 @ 0   row n: [Wih(128, l0 zero-padded) | Whh(128)]
// bias : [NL][HID] f32      : 5120   @ 655360   (b_ih + b_hh)
#define WS_WCAT_OFF 0
#define WS_BIAS_OFF 655360

__global__ void convert_weights(const float* __restrict__ Wih0,
                                const float* __restrict__ Wih,
                                const float* __restrict__ Whh,
                                const float* __restrict__ bih,
                                const float* __restrict__ bhh,
                                _Float16* __restrict__ Wcat,
                                float* __restrict__ bias) {
  int tg = blockIdx.x * blockDim.x + threadIdx.x;
  if (tg >= NL * HID * 16) return;
  int r = tg >> 4, seg = tg & 15;
  int l = r / HID, n = r % HID;
  int k0 = seg * 16;
  _Float16* dst = Wcat + (size_t)r * 256 + k0;
  if (l == 0) {
#pragma unroll
    for (int i = 0; i < 16; ++i) {
      int k = k0 + i;
      float v = 0.f;
      if (k < INP) v = Wih0[n * INP + k];
      else if (k >= HID) v = Whh[(size_t)n * HID + (k - HID)];
      dst[i] = (_Float16)v;
    }
  } else {
    const float* src = (k0 < HID)
        ? (Wih + ((size_t)(l - 1) * HID + n) * HID + k0)
        : (Whh + ((size_t)l * HID + n) * HID + (k0 - HID));
#pragma unroll
    for (int i = 0; i < 16; ++i) dst[i] = (_Float16)src[i];
  }
  if (seg == 0) bias[r] = bih[r] + bhh[r];
}

// tanh(v) = 1 - 2/(e^{2v}+1) from raw HW ops (5 VALU, 2 trans) — r6 win.
__device__ __forceinline__ float tanh_fast(float v) {
  float e = __builtin_amdgcn_exp2f(v * 2.8853900817779268f);  // e^(2v)
  float r = __builtin_amdgcn_rcpf(e + 1.f);
  return __builtin_fmaf(-2.f, r, 1.f);
}

// Light workgroup barrier: orders LDS (lgkmcnt(0)) but does NOT drain vmcnt.
__device__ __forceinline__ void barrier_light() {
  __builtin_amdgcn_sched_barrier(0);
  asm volatile("s_waitcnt lgkmcnt(0)" ::: "memory");
  __builtin_amdgcn_s_barrier();
  __builtin_amdgcn_sched_barrier(0);
}

// Round-8 = round-6 structure (147 us: 8 waves, depth-4 pipeline, 2-wave
// n-split teams, weights register-resident) with the inter-group handoff
// moved from global `seq` into LDS SEQ(t) slots. r7 settled occupancy: the
// 128 weight AGPRs + ~124 VGPRs ~ 252 combined regs/wave cap the CU at 8
// waves — 1 block/CU is the optimum, so LDS is free real estate (43.5 ->
// 161 KB, still 1 block/CU). Deletes per-tick global prefetch + store_X +
// X-reads for g1/g2, the double h-store for s3, and 57 MB of HBM writes.
// Tick tau, pt=tau&1: slot s computes t=tau-s.
//   INb: s==0 ? (g==0 ? X(pt) : SEQ(t)) : O(s-1,1-pt)
//   Hb : s==3 ? (t==0 ? Z : SEQ(t-1)) : O(s,1-pt)
//   Ob : s==3 ? SEQ(t) : O(s,pt)
// Hazards: s0 reads SEQ(t) at tick t, s3 overwrites at t+3 (3 barriers later);
// s3's SEQ(t-1) read is 1 barrier after its write; cross-group ordered by the
// group-boundary __syncthreads. ONE light barrier per tick.
__global__ __launch_bounds__(512, 2) void rnn_fused(
    const float* __restrict__ x,
    const _Float16* __restrict__ Wcat,
    const float* __restrict__ bias,
    const float* __restrict__ fcW,
    const float* __restrict__ fcb,
    float* __restrict__ out) {
  extern __shared__ __align__(16) _Float16 lds[];

  const int tid    = threadIdx.x;
  const int lane15 = tid & 15;        // batch row m (MFMA D col)
  const int quad   = (tid >> 4) & 3;  // MFMA quad -> n offset quad*4+r
  const int wid    = tid >> 6;
  const int s      = wid >> 1;        // layer slot 0..3
  const int nhalf  = wid & 1;         // n-half 0/1
  const int n0     = nhalf * 64;
  const int b0     = blockIdx.x * BB;
  // g0 x fill: 16 rows x 8 segs of 4 floats (128 threads)
  const int frow0  = tid >> 3;
  const int fc0    = (tid & 7) * 4;

  const int rdoff = lane15 * STRD + quad * 8;       // act-frag read base
  const int wroff = lane15 * STRD + n0 + quad * 4;  // D write base (+nn*16)

  half8 wf[4][8];     // weights [n-subtile][k-frag]: A-operand frags
  f32x4 bias4[4];     // bias[n0+nn*16+quad*4 .. +3]

  for (int g = 0; g < 3; ++g) {
    const int L = g * 4 + s;  // this wave's layer (>=NL -> idle slot)
    if (L < NL) {
      const _Float16* Wl = Wcat + (size_t)L * HID * 256;
#pragma unroll
      for (int nn = 0; nn < 4; ++nn) {
#pragma unroll
        for (int ks = 0; ks < 8; ++ks)
          wf[nn][ks] = *(const half8*)(Wl + (size_t)(n0 + nn * 16 + lane15) * 256 + ks * 32 + quad * 8);
        bias4[nn] = *(const f32x4*)(bias + L * HID + n0 + nn * 16 + quad * 4);
      }
    }
    // FULL barrier: prev group's LDS reads complete before re-zeroing.
    __syncthreads();
    {
      // zero O slots (2..7) + Z (8): 7 buffers. SEQ slots are never zeroed
      // (written before read; Z covers the t=0 H source).
      uint4 z; z.x = z.y = z.z = z.w = 0u;
      for (int i = tid; i < (BUFH * 7) / 8; i += 512)
        ((uint4*)(lds + 2 * BUFH))[i] = z;
    }

    f32x4 pfx[2];  // g0 prefetch (f32 x, vectorized; seg 7 = zero), slot = t&1

    auto load_next = [&](int t, int sl) {  // g0 only
      if (tid < 128) {
        const float* xb = x + ((size_t)(b0 + frow0) * SEQL + t) * INP;
        if (fc0 < INP) pfx[sl] = *(const f32x4*)(xb + fc0);  // 16B-aligned
        else { f32x4 z4 = {0.f, 0.f, 0.f, 0.f}; pfx[sl] = z4; }
      }
    };
    auto store_X = [&](int sl) {  // g0 only: pf slot sl -> LDS X slot sl
      if (tid < 128) {
        _Float16 h4[4];
#pragma unroll
        for (int i = 0; i < 4; ++i) h4[i] = (_Float16)pfx[sl][i];
        *(uint2*)(lds + sl * BUFH + frow0 * STRD + fc0) = *(const uint2*)h4;
      }
    };

    if (g == 0) {
      // prologue: t=0 into X[0] (visible after tick-0 barrier); t=1 in flight
      load_next(0, 0);
      store_X(0);
      load_next(1, 1);
    }

    auto tick = [&](int tau, int pt) {
      barrier_light();
      if (g == 0 && tau + 2 < SEQL) load_next(tau + 2, pt);  // depth-2 prefetch
      const int t = tau - s;
      if (L < NL && (unsigned)t < SEQL) {
        const _Float16* INb;
        if (s == 0) INb = (g == 0) ? lds + pt * BUFH : lds + (9 + t) * BUFH;
        else        INb = lds + (2 + 2 * (s - 1) + (1 - pt)) * BUFH;
        const _Float16* Hb = (s == 3)
            ? ((t == 0) ? lds + 8 * BUFH : lds + (9 + (t - 1)) * BUFH)
            : lds + (2 + 2 * s + (1 - pt)) * BUFH;
        _Float16* Ob = (s == 3) ? lds + (9 + t) * BUFH
                                : lds + (2 + 2 * s + pt) * BUFH;

        auto tw = [&](int nn, f32x4 av) {
          half4 o;
#pragma unroll
          for (int r = 0; r < 4; ++r) o[r] = (_Float16)tanh_fast(av[r]);
          *(half4*)(Ob + wroff + nn * 16) = o;
        };

        if (g == 0 && s == 0) {
          // layer 0: x-input is only 32 k-wide (28 + pad)
          half8 ax = *(const half8*)(INb + rdoff);
          half8 ah[4];
#pragma unroll
          for (int ks = 0; ks < 4; ++ks) ah[ks] = *(const half8*)(Hb + rdoff + ks * 32);
          f32x4 a0 = bias4[0], a1 = bias4[1];
          a0 = __builtin_amdgcn_mfma_f32_16x16x32_f16(wf[0][0], ax, a0, 0, 0, 0);
          a1 = __builtin_amdgcn_mfma_f32_16x16x32_f16(wf[1][0], ax, a1, 0, 0, 0);
#pragma unroll
          for (int ks = 0; ks < 4; ++ks) {
            a0 = __builtin_amdgcn_mfma_f32_16x16x32_f16(wf[0][4 + ks], ah[ks], a0, 0, 0, 0);
            a1 = __builtin_amdgcn_mfma_f32_16x16x32_f16(wf[1][4 + ks], ah[ks], a1, 0, 0, 0);
          }
          f32x4 a2 = bias4[2], a3 = bias4[3];
          a2 = __builtin_amdgcn_mfma_f32_16x16x32_f16(wf[2][0], ax, a2, 0, 0, 0);
          a3 = __builtin_amdgcn_mfma_f32_16x16x32_f16(wf[3][0], ax, a3, 0, 0, 0);
#pragma unroll
          for (int ks = 0; ks < 4; ++ks) {
            a2 = __builtin_amdgcn_mfma_f32_16x16x32_f16(wf[2][4 + ks], ah[ks], a2, 0, 0, 0);
            a3 = __builtin_amdgcn_mfma_f32_16x16x32_f16(wf[3][4 + ks], ah[ks], a3, 0, 0, 0);
          }
          tw(0, a0); tw(1, a1); tw(2, a2); tw(3, a3);
        } else {
          // pre-read all 8 act frags once; two 2-wide accumulator pairs so
          // pair-0's tanh (TRANS/VALU) can overlap pair-1's MFMAs.
          half8 af[8];
#pragma unroll
          for (int ks = 0; ks < 4; ++ks) af[ks] = *(const half8*)(INb + rdoff + ks * 32);
#pragma unroll
          for (int ks = 0; ks < 4; ++ks) af[4 + ks] = *(const half8*)(Hb + rdoff + ks * 32);
          f32x4 a0 = bias4[0], a1 = bias4[1];
#pragma unroll
          for (int i = 0; i < 8; ++i) {
            a0 = __builtin_amdgcn_mfma_f32_16x16x32_f16(wf[0][i], af[i], a0, 0, 0, 0);
            a1 = __builtin_amdgcn_mfma_f32_16x16x32_f16(wf[1][i], af[i], a1, 0, 0, 0);
          }
          f32x4 a2 = bias4[2], a3 = bias4[3];
#pragma unroll
          for (int i = 0; i < 8; ++i) {
            a2 = __builtin_amdgcn_mfma_f32_16x16x32_f16(wf[2][i], af[i], a2, 0, 0, 0);
            a3 = __builtin_amdgcn_mfma_f32_16x16x32_f16(wf[3][i], af[i], a3, 0, 0, 0);
          }
          tw(0, a0); tw(1, a1); tw(2, a2); tw(3, a3);
        }
      }
      if (g == 0 && tau + 1 < SEQL) store_X(1 - pt);  // t=tau+1 -> X[(tau+1)&1]
    };

    const int Tend = (g == 2) ? 28 : 30;  // even; ticks 0..Tend
    for (int tau = 0; tau < Tend; tau += 2) {
      tick(tau, 0);
      tick(tau + 1, 1);
    }
    tick(Tend, 0);
  }
  __syncthreads();

  // --- FC on layer-9 h at t=27: slot s=1, written at g2 tick 28 (pt=0) -> O(1,0) = slot 4 ---
  if (tid < BB * NC) {
    int c = tid >> 4;
    int b = tid & 15;
    float acc = fcb[c];
    const float* wr = fcW + c * HID;
    const _Float16* hr = lds + BUFH * 4 + b * STRD;
#pragma unroll
    for (int k0 = 0; k0 < HID; k0 += 8) {
      half8 h = *(const half8*)(hr + k0);
      f32x4 w0 = *(const f32x4*)(wr + k0);
      f32x4 w1 = *(const f32x4*)(wr + k0 + 4);
#pragma unroll
      for (int j = 0; j < 4; ++j)
        acc += (float)h[j] * w0[j] + (float)h[j + 4] * w1[j];
    }
    out[(size_t)(b0 + b) * NC + c] = acc;
  }
}

extern "C" void kernel_launch(void* const* d_in, const int* in_sizes, int n_in,
                              void* d_out, int out_size, void* d_ws, size_t ws_size,
                              hipStream_t stream) {
  const float* x    = (const float*)d_in[0];
  const float* Wih0 = (const float*)d_in[1];
  const float* Wih  = (const float*)d_in[2];
  const float* Whh  = (const float*)d_in[3];
  const float* bih  = (const float*)d_in[4];
  const float* bhh  = (const float*)d_in[5];
  const float* fcW  = (const float*)d_in[6];
  const float* fcb  = (const float*)d_in[7];
  float* out = (float*)d_out;

  _Float16* Wcat = (_Float16*)((char*)d_ws + WS_WCAT_OFF);
  float*    bs   = (float*)((char*)d_ws + WS_BIAS_OFF);

  static bool attr_done = false;
  if (!attr_done) {
    hipFuncSetAttribute(reinterpret_cast<const void*>(rnn_fused),
                        hipFuncAttributeMaxDynamicSharedMemorySize, LDS_BYTES);
    attr_done = true;
  }

  convert_weights<<<dim3(80), dim3(256), 0, stream>>>(Wih0, Wih, Whh, bih, bhh, Wcat, bs);
  rnn_fused<<<dim3(BATCH / BB), dim3(512), LDS_BYTES, stream>>>(x, Wcat, bs, fcW, fcb, out);
}